// Round 1
// baseline (17791.393 us; speedup 1.0000x reference)
//
#include <hip/hip_runtime.h>
#include <math.h>

#define BB 32
#define TT 2048
#define FF 16
#define CC 17
#define HH 64

__device__ __forceinline__ float rl(float v, int lane) {
    return __int_as_float(__builtin_amdgcn_readlane(__float_as_int(v), lane));
}

// One block per batch element. 8 waves x 64 lanes.
// Wave w owns: k-slice [8w,8w+8) of each hidden matrix (whid[4][8]),
//              out columns c0=2w, c1=2w+1 for every h=lane (wo0/wo1[64]),
//              k-slice of the c=16 out column (w16[8]).
__launch_bounds__(512, 2)
__global__ void ncde_main(const float* __restrict__ x,
                          const float* __restrict__ wi1, const float* __restrict__ bi1,
                          const float* __restrict__ wi2, const float* __restrict__ bi2,
                          const float* __restrict__ w_in, const float* __restrict__ b_in,
                          const float* __restrict__ w_hid, const float* __restrict__ b_hid,
                          const float* __restrict__ w_out, const float* __restrict__ b_out,
                          float* __restrict__ zT)
{
    const int b   = blockIdx.x;
    const int tid = threadIdx.x;
    const int w   = tid >> 6;
    const int l   = tid & 63;

    __shared__ float ph[4][8][64];   // hidden-layer partials
    __shared__ float pgs[8][64];     // per-wave partial g
    __shared__ float p16s[8][64];    // partials of u16 (c=16 column)

    // ---- load weights into registers ----
    float whid[4][8];
    #pragma unroll
    for (int kk = 0; kk < 8; ++kk) {
        int k = 8 * w + kk;
        whid[0][kk] = w_in[k * HH + l];
        whid[1][kk] = w_hid[(0 * HH + k) * HH + l];
        whid[2][kk] = w_hid[(1 * HH + k) * HH + l];
        whid[3][kk] = w_hid[(2 * HH + k) * HH + l];
    }
    float bh[4] = { b_in[l], b_hid[0 * HH + l], b_hid[1 * HH + l], b_hid[2 * HH + l] };

    const int c0 = 2 * w, c1 = 2 * w + 1;    // c1 <= 15; c=16 handled separately
    float wo0[64], wo1[64], w16[8];
    #pragma unroll
    for (int k = 0; k < 64; ++k) {
        wo0[k] = w_out[k * (CC * HH) + l * CC + c0];
        wo1[k] = w_out[k * (CC * HH) + l * CC + c1];
    }
    #pragma unroll
    for (int kk = 0; kk < 8; ++kk)
        w16[kk] = w_out[(8 * w + kk) * (CC * HH) + l * CC + 16];
    const float bo0  = b_out[l * CC + c0];
    const float bo1  = b_out[l * CC + c1];
    const float bo16 = b_out[l * CC + 16];

    // ---- z0 = relu(xa0 @ wi1 + bi1) @ wi2 + bi2 ; xa0 = [0, x[b,0,:]] ----
    float h0 = bi1[l];
    #pragma unroll
    for (int c = 1; c < CC; ++c) {
        float xc = x[(b * TT + 0) * FF + (c - 1)];
        h0 = fmaf(xc, wi1[c * HH + l], h0);   // c==0 term multiplied by t=0 -> skip
    }
    h0 = fmaxf(h0, 0.0f);
    float z = bi2[l];
    #pragma unroll
    for (int k = 0; k < 64; ++k)
        z = fmaf(rl(h0, k), wi2[k * HH + l], z);

    if (w == 0) zT[(b * TT + 0) * HH + l] = z;

    // ---- g(zin, xd) for this wave's channels ----
    auto G = [&](float zin, float xd0, float xd1, float xd16) -> float {
        float cur = zin;
        #pragma unroll
        for (int layer = 0; layer < 4; ++layer) {
            float acc = 0.0f;
            #pragma unroll
            for (int kk = 0; kk < 8; ++kk)
                acc = fmaf(rl(cur, 8 * w + kk), whid[layer][kk], acc);
            ph[layer][w][l] = acc;
            __syncthreads();
            float nx = bh[layer];
            #pragma unroll
            for (int g = 0; g < 8; ++g) nx += ph[layer][g][l];
            cur = fmaxf(nx, 0.0f);
        }
        // out layer: u[c] = b_out[l*17+c] + sum_k hh[k] * w_out[k][l*17+c]
        float u0 = bo0, u1 = bo1, a16 = 0.0f;
        #pragma unroll
        for (int k = 0; k < 64; ++k) {
            float s = rl(cur, k);
            u0 = fmaf(s, wo0[k], u0);
            u1 = fmaf(s, wo1[k], u1);
        }
        #pragma unroll
        for (int kk = 0; kk < 8; ++kk)
            a16 = fmaf(rl(cur, 8 * w + kk), w16[kk], a16);

        float pg = tanhf(u0) * xd0 + tanhf(u1) * xd1;
        pgs[w][l]  = pg;
        p16s[w][l] = a16;
        __syncthreads();
        float u16 = bo16, gsum = 0.0f;
        #pragma unroll
        for (int g = 0; g < 8; ++g) { u16 += p16s[g][l]; gsum += pgs[g][l]; }
        gsum = fmaf(tanhf(u16), xd16, gsum);
        return gsum;
    };

    // ---- time scan ----
    const float* xb = x + (size_t)b * TT * FF;
    float dp0 = 0.f, dp1 = 0.f, dp16 = 0.f;
    #pragma unroll 1
    for (int t = 0; t < TT - 1; ++t) {
        // diffs[t][c]: channel 0 is time (always 1), channel c>=1 is x[:,c-1]
        float dc0  = (c0 == 0) ? 1.0f : (xb[(t + 1) * FF + (c0 - 1)] - xb[t * FF + (c0 - 1)]);
        float dc1  = xb[(t + 1) * FF + (c1 - 1)] - xb[t * FF + (c1 - 1)];
        float dc16 = xb[(t + 1) * FF + 15] - xb[t * FF + 15];
        if (t == 0) { dp0 = dc0; dp1 = dc1; dp16 = dc16; }

        // deriv(2/3) = a + (4/3)(b-a)
        const float f43 = 4.0f / 3.0f;
        float x20  = dp0  + f43 * (dc0  - dp0);
        float x21  = dp1  + f43 * (dc1  - dp1);
        float x216 = dp16 + f43 * (dc16 - dp16);

        float k1 = G(z, dp0, dp1, dp16);
        float k2 = G(z + k1 * (1.0f / 3.0f), dc0, dc1, dc16);
        float k3 = G(z + (k2 - k1 * (1.0f / 3.0f)), x20, x21, x216);
        float k4 = G(z + (k1 - k2 + k3), dc0, dc1, dc16);
        z = z + 0.125f * (k1 + 3.0f * (k2 + k3) + k4);

        if (w == 0) zT[(b * TT + (t + 1)) * HH + l] = z;
        dp0 = dc0; dp1 = dc1; dp16 = dc16;
    }
}

// out = gelu_exact(zT) @ w_proj + b_proj ; mask = 0
__global__ void ncde_proj(const float* __restrict__ zT,
                          const float* __restrict__ w_proj, const float* __restrict__ b_proj,
                          float* __restrict__ out, float* __restrict__ mask)
{
    __shared__ float gz[16][64];
    const int blk = blockIdx.x;          // B*T/16 blocks
    const int tid = threadIdx.x;         // 256
    const int r16 = tid >> 4, f = tid & 15;
    const int row0 = blk * 16;

    #pragma unroll
    for (int i = 0; i < 4; ++i) {
        int idx = tid + i * 256;         // 0..1023
        int r = idx >> 6, k = idx & 63;
        float zv = zT[(size_t)(row0 + r) * HH + k];
        gz[r][k] = 0.5f * zv * (1.0f + erff(zv * 0.70710678118654752f));
    }
    __syncthreads();

    float acc = b_proj[f];
    #pragma unroll
    for (int k = 0; k < 64; ++k)
        acc = fmaf(gz[r16][k], w_proj[k * FF + f], acc);
    out[(size_t)(row0 + r16) * FF + f] = acc;
    if (f == 0) mask[row0 + r16] = 0.0f;
}

extern "C" void kernel_launch(void* const* d_in, const int* in_sizes, int n_in,
                              void* d_out, int out_size, void* d_ws, size_t ws_size,
                              hipStream_t stream)
{
    (void)in_sizes; (void)n_in; (void)d_ws; (void)ws_size; (void)out_size;
    const float* x      = (const float*)d_in[0];
    const float* wi1    = (const float*)d_in[1];
    const float* bi1    = (const float*)d_in[2];
    const float* wi2    = (const float*)d_in[3];
    const float* bi2    = (const float*)d_in[4];
    const float* w_in   = (const float*)d_in[5];
    const float* b_in   = (const float*)d_in[6];
    const float* w_hid  = (const float*)d_in[7];
    const float* b_hid  = (const float*)d_in[8];
    const float* w_out  = (const float*)d_in[9];
    const float* b_out  = (const float*)d_in[10];
    const float* w_proj = (const float*)d_in[11];
    const float* b_proj = (const float*)d_in[12];

    float* zT   = (float*)d_out;                       // B*T*H
    float* outp = zT + (size_t)BB * TT * HH;           // B*T*F
    float* mask = outp + (size_t)BB * TT * FF;         // B*T

    ncde_main<<<dim3(BB), dim3(512), 0, stream>>>(
        x, wi1, bi1, wi2, bi2, w_in, b_in, w_hid, b_hid, w_out, b_out, zT);
    ncde_proj<<<dim3((BB * TT) / 16), dim3(256), 0, stream>>>(
        zT, w_proj, b_proj, outp, mask);
}

// Round 2
// 15453.082 us; speedup vs baseline: 1.1513x; 1.1513x over previous
//
#include <hip/hip_runtime.h>
#include <math.h>

#define BB 32
#define TT 2048
#define FF 16
#define CC 17
#define HH 64

__device__ __forceinline__ float rl(float v, int lane) {
    return __int_as_float(__builtin_amdgcn_readlane(__float_as_int(v), lane));
}

// fast tanh: 1 - 2/(exp(2x)+1) via v_exp_f32 + v_rcp_f32 (tolerance is ~1e-2, this is ~1e-6)
__device__ __forceinline__ float ftanh(float x) {
    float e = __builtin_amdgcn_exp2f(x * 2.88539008177792681472f); // exp(2x)
    return 1.0f - 2.0f * __builtin_amdgcn_rcpf(e + 1.0f);
}

#define PIN(v) asm volatile("" : "+v"(v))

// One block per batch element. 8 waves x 64 lanes.
// Wave w owns: k-slice [8w,8w+8) of each hidden matrix (whid[4][8]),
//              out columns c0=2w, c1=2w+1 for every h=lane (wo0/wo1[64]),
//              k-slice of the c=16 out column (w16[8]).
__launch_bounds__(512, 2)
__global__ void ncde_main(const float* __restrict__ x,
                          const float* __restrict__ wi1, const float* __restrict__ bi1,
                          const float* __restrict__ wi2, const float* __restrict__ bi2,
                          const float* __restrict__ w_in, const float* __restrict__ b_in,
                          const float* __restrict__ w_hid, const float* __restrict__ b_hid,
                          const float* __restrict__ w_out, const float* __restrict__ b_out,
                          float* __restrict__ zT)
{
    const int b   = blockIdx.x;
    const int tid = threadIdx.x;
    const int w   = tid >> 6;
    const int l   = tid & 63;

    __shared__ float ph[4][8][64];   // hidden-layer partials (per-layer buffer, conflict-free)
    __shared__ float pgs[8][64];     // per-wave partial g
    __shared__ float p16s[8][64];    // partials of u16 (c=16 column)

    // ---- load weights into registers ----
    float whid[4][8];
    #pragma unroll
    for (int kk = 0; kk < 8; ++kk) {
        int k = 8 * w + kk;
        whid[0][kk] = w_in[k * HH + l];
        whid[1][kk] = w_hid[(0 * HH + k) * HH + l];
        whid[2][kk] = w_hid[(1 * HH + k) * HH + l];
        whid[3][kk] = w_hid[(2 * HH + k) * HH + l];
    }
    float bh[4] = { b_in[l], b_hid[0 * HH + l], b_hid[1 * HH + l], b_hid[2 * HH + l] };

    const int c0 = 2 * w, c1 = 2 * w + 1;    // c1 <= 15; c=16 handled separately
    float wo0[64], wo1[64], w16[8];
    #pragma unroll
    for (int k = 0; k < 64; ++k) {
        wo0[k] = w_out[k * (CC * HH) + l * CC + c0];
        wo1[k] = w_out[k * (CC * HH) + l * CC + c1];
    }
    #pragma unroll
    for (int kk = 0; kk < 8; ++kk)
        w16[kk] = w_out[(8 * w + kk) * (CC * HH) + l * CC + 16];
    float bo0  = b_out[l * CC + c0];
    float bo1  = b_out[l * CC + c1];
    float bo16 = b_out[l * CC + 16];

    // ---- pin all loop-invariant weights in registers: forbids the register
    // allocator from rematerializing (re-loading) them inside the t-loop,
    // which is exactly what it did at VGPR_Count=112 (R1). ----
    #pragma unroll
    for (int k = 0; k < 64; ++k) { PIN(wo0[k]); PIN(wo1[k]); }
    #pragma unroll
    for (int kk = 0; kk < 8; ++kk) {
        PIN(w16[kk]);
        PIN(whid[0][kk]); PIN(whid[1][kk]); PIN(whid[2][kk]); PIN(whid[3][kk]);
    }
    #pragma unroll
    for (int i = 0; i < 4; ++i) PIN(bh[i]);
    PIN(bo0); PIN(bo1); PIN(bo16);

    // ---- z0 = relu(xa0 @ wi1 + bi1) @ wi2 + bi2 ; xa0 = [0, x[b,0,:]] ----
    float h0 = bi1[l];
    #pragma unroll
    for (int c = 1; c < CC; ++c) {
        float xc = x[(b * TT + 0) * FF + (c - 1)];
        h0 = fmaf(xc, wi1[c * HH + l], h0);   // c==0 term multiplied by t=0 -> skip
    }
    h0 = fmaxf(h0, 0.0f);
    float z = bi2[l];
    #pragma unroll
    for (int k = 0; k < 64; ++k)
        z = fmaf(rl(h0, k), wi2[k * HH + l], z);

    if (w == 0) zT[(b * TT + 0) * HH + l] = z;

    // ---- g(zin, xd) for this wave's channels ----
    auto G = [&](float zin, float xd0, float xd1, float xd16) -> float {
        float cur = zin;
        #pragma unroll
        for (int layer = 0; layer < 4; ++layer) {
            float a0 = 0.0f, a1 = 0.0f;
            #pragma unroll
            for (int kk = 0; kk < 8; kk += 2) {
                float s0 = rl(cur, 8 * w + kk);
                float s1 = rl(cur, 8 * w + kk + 1);
                a0 = fmaf(s0, whid[layer][kk],     a0);
                a1 = fmaf(s1, whid[layer][kk + 1], a1);
            }
            ph[layer][w][l] = a0 + a1;
            __syncthreads();
            float r0 = ph[layer][0][l], r1 = ph[layer][1][l];
            float r2 = ph[layer][2][l], r3 = ph[layer][3][l];
            float r4 = ph[layer][4][l], r5 = ph[layer][5][l];
            float r6 = ph[layer][6][l], r7 = ph[layer][7][l];
            float nx = (((r0 + r1) + (r2 + r3)) + ((r4 + r5) + (r6 + r7))) + bh[layer];
            cur = fmaxf(nx, 0.0f);
        }
        // out layer: u[c] = b_out[l*17+c] + sum_k hh[k] * w_out[k][l*17+c]
        float u0a = bo0, u0b = 0.0f, u1a = bo1, u1b = 0.0f;
        #pragma unroll
        for (int k = 0; k < 64; k += 2) {
            float s0 = rl(cur, k);
            float s1 = rl(cur, k + 1);
            u0a = fmaf(s0, wo0[k],     u0a);
            u1a = fmaf(s0, wo1[k],     u1a);
            u0b = fmaf(s1, wo0[k + 1], u0b);
            u1b = fmaf(s1, wo1[k + 1], u1b);
        }
        float a16a = 0.0f, a16b = 0.0f;
        #pragma unroll
        for (int kk = 0; kk < 8; kk += 2) {
            a16a = fmaf(rl(cur, 8 * w + kk),     w16[kk],     a16a);
            a16b = fmaf(rl(cur, 8 * w + kk + 1), w16[kk + 1], a16b);
        }
        float pg = ftanh(u0a + u0b) * xd0 + ftanh(u1a + u1b) * xd1;
        pgs[w][l]  = pg;
        p16s[w][l] = a16a + a16b;
        __syncthreads();
        float g0 = pgs[0][l], g1 = pgs[1][l], g2 = pgs[2][l], g3 = pgs[3][l];
        float g4 = pgs[4][l], g5 = pgs[5][l], g6 = pgs[6][l], g7 = pgs[7][l];
        float q0 = p16s[0][l], q1 = p16s[1][l], q2 = p16s[2][l], q3 = p16s[3][l];
        float q4 = p16s[4][l], q5 = p16s[5][l], q6 = p16s[6][l], q7 = p16s[7][l];
        float u16  = (((q0 + q1) + (q2 + q3)) + ((q4 + q5) + (q6 + q7))) + bo16;
        float gsum = ((g0 + g1) + (g2 + g3)) + ((g4 + g5) + (g6 + g7));
        return fmaf(ftanh(u16), xd16, gsum);
    };

    // ---- time scan ----
    const float* xb = x + (size_t)b * TT * FF;
    float dp0 = 0.f, dp1 = 0.f, dp16 = 0.f;
    #pragma unroll 1
    for (int t = 0; t < TT - 1; ++t) {
        // diffs[t][c]: channel 0 is time (always 1), channel c>=1 is x[:,c-1]
        float dc0  = (c0 == 0) ? 1.0f : (xb[(t + 1) * FF + (c0 - 1)] - xb[t * FF + (c0 - 1)]);
        float dc1  = xb[(t + 1) * FF + (c1 - 1)] - xb[t * FF + (c1 - 1)];
        float dc16 = xb[(t + 1) * FF + 15] - xb[t * FF + 15];
        if (t == 0) { dp0 = dc0; dp1 = dc1; dp16 = dc16; }

        // deriv(2/3) = a + (4/3)(b-a)
        const float f43 = 4.0f / 3.0f;
        float x20  = dp0  + f43 * (dc0  - dp0);
        float x21  = dp1  + f43 * (dc1  - dp1);
        float x216 = dp16 + f43 * (dc16 - dp16);

        float k1 = G(z, dp0, dp1, dp16);
        float k2 = G(z + k1 * (1.0f / 3.0f), dc0, dc1, dc16);
        float k3 = G(z + (k2 - k1 * (1.0f / 3.0f)), x20, x21, x216);
        float k4 = G(z + (k1 - k2 + k3), dc0, dc1, dc16);
        z = z + 0.125f * (k1 + 3.0f * (k2 + k3) + k4);

        if (w == 0) zT[(b * TT + (t + 1)) * HH + l] = z;
        dp0 = dc0; dp1 = dc1; dp16 = dc16;
    }
}

// out = gelu_exact(zT) @ w_proj + b_proj ; mask = 0
__global__ void ncde_proj(const float* __restrict__ zT,
                          const float* __restrict__ w_proj, const float* __restrict__ b_proj,
                          float* __restrict__ out, float* __restrict__ mask)
{
    __shared__ float gz[16][64];
    const int blk = blockIdx.x;          // B*T/16 blocks
    const int tid = threadIdx.x;         // 256
    const int r16 = tid >> 4, f = tid & 15;
    const int row0 = blk * 16;

    #pragma unroll
    for (int i = 0; i < 4; ++i) {
        int idx = tid + i * 256;         // 0..1023
        int r = idx >> 6, k = idx & 63;
        float zv = zT[(size_t)(row0 + r) * HH + k];
        gz[r][k] = 0.5f * zv * (1.0f + erff(zv * 0.70710678118654752f));
    }
    __syncthreads();

    float acc = b_proj[f];
    #pragma unroll
    for (int k = 0; k < 64; ++k)
        acc = fmaf(gz[r16][k], w_proj[k * FF + f], acc);
    out[(size_t)(row0 + r16) * FF + f] = acc;
    if (f == 0) mask[row0 + r16] = 0.0f;
}

extern "C" void kernel_launch(void* const* d_in, const int* in_sizes, int n_in,
                              void* d_out, int out_size, void* d_ws, size_t ws_size,
                              hipStream_t stream)
{
    (void)in_sizes; (void)n_in; (void)d_ws; (void)ws_size; (void)out_size;
    const float* x      = (const float*)d_in[0];
    const float* wi1    = (const float*)d_in[1];
    const float* bi1    = (const float*)d_in[2];
    const float* wi2    = (const float*)d_in[3];
    const float* bi2    = (const float*)d_in[4];
    const float* w_in   = (const float*)d_in[5];
    const float* b_in   = (const float*)d_in[6];
    const float* w_hid  = (const float*)d_in[7];
    const float* b_hid  = (const float*)d_in[8];
    const float* w_out  = (const float*)d_in[9];
    const float* b_out  = (const float*)d_in[10];
    const float* w_proj = (const float*)d_in[11];
    const float* b_proj = (const float*)d_in[12];

    float* zT   = (float*)d_out;                       // B*T*H
    float* outp = zT + (size_t)BB * TT * HH;           // B*T*F
    float* mask = outp + (size_t)BB * TT * FF;         // B*T

    ncde_main<<<dim3(BB), dim3(512), 0, stream>>>(
        x, wi1, bi1, wi2, bi2, w_in, b_in, w_hid, b_hid, w_out, b_out, zT);
    ncde_proj<<<dim3((BB * TT) / 16), dim3(256), 0, stream>>>(
        zT, w_proj, b_proj, outp, mask);
}

// Round 3
// 13276.234 us; speedup vs baseline: 1.3401x; 1.1640x over previous
//
#include <hip/hip_runtime.h>
#include <math.h>

#define BB 32
#define TT 2048
#define FF 16
#define CC 17
#define HH 64

typedef float v2f __attribute__((ext_vector_type(2)));
typedef float v4f __attribute__((ext_vector_type(4)));

__device__ __forceinline__ float rl(float v, int lane) {
    return __int_as_float(__builtin_amdgcn_readlane(__float_as_int(v), lane));
}

// fast tanh: 1 - 2/(exp(2x)+1) via v_exp_f32 + v_rcp_f32 (~1e-6 abs err)
__device__ __forceinline__ float ftanh(float x) {
    float e = __builtin_amdgcn_exp2f(x * 2.88539008177792681472f); // exp(2x)
    return 1.0f - 2.0f * __builtin_amdgcn_rcpf(e + 1.0f);
}

#define PIN(v) asm volatile("" : "+v"(v))
#define PIN2(v) do { double _d = __builtin_bit_cast(double, v); \
                     asm volatile("" : "+v"(_d));               \
                     v = __builtin_bit_cast(v2f, _d); } while (0)

// One block per batch element. 8 waves x 64 lanes.
// Wave w owns: k-slice [8w,8w+8) of each hidden matrix (whid[4][8]),
//              out column pair (c0,c1)=(2w,2w+1) for every h=lane (wopk[64] as float2),
//              k-slice of the c=16 out column (w16[8]).
// amdgpu_waves_per_eu(2,2): grid=32 -> 1 block/CU -> exactly 2 waves/SIMD; this
// grants the 256-VGPR budget so the ~170 weight values stay register-resident
// (R1/R2 showed the backend capping at 112 VGPRs targeting useless occupancy).
__attribute__((amdgpu_waves_per_eu(2, 2)))
__launch_bounds__(512)
__global__ void ncde_main(const float* __restrict__ x,
                          const float* __restrict__ wi1, const float* __restrict__ bi1,
                          const float* __restrict__ wi2, const float* __restrict__ bi2,
                          const float* __restrict__ w_in, const float* __restrict__ b_in,
                          const float* __restrict__ w_hid, const float* __restrict__ b_hid,
                          const float* __restrict__ w_out, const float* __restrict__ b_out,
                          float* __restrict__ zT)
{
    const int b   = blockIdx.x;
    const int tid = threadIdx.x;
    const int w   = tid >> 6;
    const int l   = tid & 63;

    __shared__ float ph[4][8][64];            // hidden-layer partials [layer][wave][h]
    __shared__ __align__(16) float hbuf[64];  // published last-hidden activation
    __shared__ v2f  pgq[8][64];               // (pg, a16) partials per wave

    // ---- load weights into registers ----
    float whid[4][8];
    #pragma unroll
    for (int kk = 0; kk < 8; ++kk) {
        int k = 8 * w + kk;
        whid[0][kk] = w_in[k * HH + l];
        whid[1][kk] = w_hid[(0 * HH + k) * HH + l];
        whid[2][kk] = w_hid[(1 * HH + k) * HH + l];
        whid[3][kk] = w_hid[(2 * HH + k) * HH + l];
    }
    // biases folded into wave 0's partial sums
    float bfold[4];
    bfold[0] = (w == 0) ? b_in[l] : 0.0f;
    bfold[1] = (w == 0) ? b_hid[0 * HH + l] : 0.0f;
    bfold[2] = (w == 0) ? b_hid[1 * HH + l] : 0.0f;
    bfold[3] = (w == 0) ? b_hid[2 * HH + l] : 0.0f;

    const int c0 = 2 * w, c1 = 2 * w + 1;    // c1 <= 15; c=16 handled separately
    v2f wopk[64];
    #pragma unroll
    for (int k = 0; k < 64; ++k) {
        wopk[k].x = w_out[k * (CC * HH) + l * CC + c0];
        wopk[k].y = w_out[k * (CC * HH) + l * CC + c1];
    }
    float w16[8];
    #pragma unroll
    for (int kk = 0; kk < 8; ++kk)
        w16[kk] = w_out[(8 * w + kk) * (CC * HH) + l * CC + 16];
    float bo0   = b_out[l * CC + c0];
    float bo1   = b_out[l * CC + c1];
    float bo16f = (w == 0) ? b_out[l * CC + 16] : 0.0f;   // folded into wave0 a16 partial

    // pin all loop-invariant weights (with the 256-reg budget they now fit)
    #pragma unroll
    for (int k = 0; k < 64; ++k) PIN2(wopk[k]);
    #pragma unroll
    for (int kk = 0; kk < 8; ++kk) {
        PIN(w16[kk]);
        PIN(whid[0][kk]); PIN(whid[1][kk]); PIN(whid[2][kk]); PIN(whid[3][kk]);
    }
    #pragma unroll
    for (int i = 0; i < 4; ++i) PIN(bfold[i]);
    PIN(bo0); PIN(bo1); PIN(bo16f);

    // ---- z0 = relu(xa0 @ wi1 + bi1) @ wi2 + bi2 ; xa0 = [0, x[b,0,:]] ----
    float h0 = bi1[l];
    #pragma unroll
    for (int c = 1; c < CC; ++c) {
        float xc = x[(b * TT + 0) * FF + (c - 1)];
        h0 = fmaf(xc, wi1[c * HH + l], h0);
    }
    h0 = fmaxf(h0, 0.0f);
    float z = bi2[l];
    #pragma unroll
    for (int k = 0; k < 64; ++k)
        z = fmaf(rl(h0, k), wi2[k * HH + l], z);

    if (w == 0) zT[(b * TT + 0) * HH + l] = z;

    // ---- g(zin, xd) for this wave's channels ----
    auto G = [&](float zin, float xd0, float xd1, float xd16) -> float {
        float cur = zin;
        #pragma unroll
        for (int layer = 0; layer < 4; ++layer) {
            float a0 = bfold[layer], a1 = 0.0f;
            #pragma unroll
            for (int kk = 0; kk < 8; kk += 2) {
                float s0 = rl(cur, 8 * w + kk);
                float s1 = rl(cur, 8 * w + kk + 1);
                a0 = fmaf(s0, whid[layer][kk],     a0);
                a1 = fmaf(s1, whid[layer][kk + 1], a1);
            }
            ph[layer][w][l] = a0 + a1;
            __syncthreads();
            float r0 = ph[layer][0][l], r1 = ph[layer][1][l];
            float r2 = ph[layer][2][l], r3 = ph[layer][3][l];
            float r4 = ph[layer][4][l], r5 = ph[layer][5][l];
            float r6 = ph[layer][6][l], r7 = ph[layer][7][l];
            float nx = ((r0 + r1) + (r2 + r3)) + ((r4 + r5) + (r6 + r7));
            cur = fmaxf(nx, 0.0f);
        }
        // publish hh once; everyone broadcasts from LDS (kills 72 readlanes/wave)
        if (w == 0) hbuf[l] = cur;
        __syncthreads();

        // out layer: (u0,u1) += hh[k] * (wo[k][c0], wo[k][c1]) via v_pk_fma_f32
        v2f u0 = { bo0, bo1 }, u1 = { 0.f, 0.f }, u2 = { 0.f, 0.f }, u3 = { 0.f, 0.f };
        #pragma unroll
        for (int j = 0; j < 16; ++j) {
            v4f q = *reinterpret_cast<const v4f*>(&hbuf[4 * j]);  // uniform-addr b128 broadcast
            u0 += wopk[4 * j + 0] * q.x;
            u1 += wopk[4 * j + 1] * q.y;
            u2 += wopk[4 * j + 2] * q.z;
            u3 += wopk[4 * j + 3] * q.w;
        }
        v2f ut = (u0 + u1) + (u2 + u3);

        // c16 slice from broadcast regs (no readlane)
        v4f qa = *reinterpret_cast<const v4f*>(&hbuf[8 * w]);
        v4f qb = *reinterpret_cast<const v4f*>(&hbuf[8 * w + 4]);
        float a16a = bo16f, a16b = 0.0f;
        a16a = fmaf(qa.x, w16[0], a16a); a16b = fmaf(qa.y, w16[1], a16b);
        a16a = fmaf(qa.z, w16[2], a16a); a16b = fmaf(qa.w, w16[3], a16b);
        a16a = fmaf(qb.x, w16[4], a16a); a16b = fmaf(qb.y, w16[5], a16b);
        a16a = fmaf(qb.z, w16[6], a16a); a16b = fmaf(qb.w, w16[7], a16b);

        float pg = ftanh(ut.x) * xd0 + ftanh(ut.y) * xd1;
        pgq[w][l] = (v2f){ pg, a16a + a16b };
        __syncthreads();
        v2f s0 = pgq[0][l], s1 = pgq[1][l], s2 = pgq[2][l], s3 = pgq[3][l];
        v2f s4 = pgq[4][l], s5 = pgq[5][l], s6 = pgq[6][l], s7 = pgq[7][l];
        v2f st = ((s0 + s1) + (s2 + s3)) + ((s4 + s5) + (s6 + s7));
        return fmaf(ftanh(st.y), xd16, st.x);
    };

    // ---- time scan ----
    const float* xb = x + (size_t)b * TT * FF;
    const bool hasc0 = (w != 0);
    const int  f0 = 2 * w - 1;   // x feature for c0 (valid iff hasc0)
    const int  f1 = 2 * w;       // x feature for c1
    // carried x values (halves the per-t global loads)
    float xp0 = hasc0 ? xb[0 * FF + f0] : 0.0f;
    float xp1 = xb[0 * FF + f1];
    float xp16 = xb[0 * FF + 15];
    float xn0 = hasc0 ? xb[1 * FF + f0] : 0.0f;
    float xn1 = xb[1 * FF + f1];
    float xn16 = xb[1 * FF + 15];
    float dc0 = hasc0 ? (xn0 - xp0) : 1.0f;
    float dc1 = xn1 - xp1;
    float dc16 = xn16 - xp16;
    float dp0 = dc0, dp1 = dc1, dp16 = dc16;
    xp0 = xn0; xp1 = xn1; xp16 = xn16;

    #pragma unroll 1
    for (int t = 0; t < TT - 1; ++t) {
        const float f43 = 4.0f / 3.0f;
        float x20  = dp0  + f43 * (dc0  - dp0);
        float x21  = dp1  + f43 * (dc1  - dp1);
        float x216 = dp16 + f43 * (dc16 - dp16);

        // prefetch next x row (clamped at the tail; value unused there)
        int tn = (t + 2 < TT) ? (t + 2) : (TT - 1);
        float yn0 = hasc0 ? xb[tn * FF + f0] : 0.0f;
        float yn1 = xb[tn * FF + f1];
        float yn16 = xb[tn * FF + 15];

        float k1 = G(z, dp0, dp1, dp16);
        float k2 = G(z + k1 * (1.0f / 3.0f), dc0, dc1, dc16);
        float k3 = G(z + (k2 - k1 * (1.0f / 3.0f)), x20, x21, x216);
        float k4 = G(z + (k1 - k2 + k3), dc0, dc1, dc16);
        z = z + 0.125f * (k1 + 3.0f * (k2 + k3) + k4);

        if (w == 0) zT[(b * TT + (t + 1)) * HH + l] = z;

        dp0 = dc0; dp1 = dc1; dp16 = dc16;
        dc0 = hasc0 ? (yn0 - xp0) : 1.0f;
        dc1 = yn1 - xp1;
        dc16 = yn16 - xp16;
        xp0 = yn0; xp1 = yn1; xp16 = yn16;
    }
}

// out = gelu_exact(zT) @ w_proj + b_proj ; mask = 0
__global__ void ncde_proj(const float* __restrict__ zT,
                          const float* __restrict__ w_proj, const float* __restrict__ b_proj,
                          float* __restrict__ out, float* __restrict__ mask)
{
    __shared__ float gz[16][64];
    const int blk = blockIdx.x;          // B*T/16 blocks
    const int tid = threadIdx.x;         // 256
    const int r16 = tid >> 4, f = tid & 15;
    const int row0 = blk * 16;

    #pragma unroll
    for (int i = 0; i < 4; ++i) {
        int idx = tid + i * 256;         // 0..1023
        int r = idx >> 6, k = idx & 63;
        float zv = zT[(size_t)(row0 + r) * HH + k];
        gz[r][k] = 0.5f * zv * (1.0f + erff(zv * 0.70710678118654752f));
    }
    __syncthreads();

    float acc = b_proj[f];
    #pragma unroll
    for (int k = 0; k < 64; ++k)
        acc = fmaf(gz[r16][k], w_proj[k * FF + f], acc);
    out[(size_t)(row0 + r16) * FF + f] = acc;
    if (f == 0) mask[row0 + r16] = 0.0f;
}

extern "C" void kernel_launch(void* const* d_in, const int* in_sizes, int n_in,
                              void* d_out, int out_size, void* d_ws, size_t ws_size,
                              hipStream_t stream)
{
    (void)in_sizes; (void)n_in; (void)d_ws; (void)ws_size; (void)out_size;
    const float* x      = (const float*)d_in[0];
    const float* wi1    = (const float*)d_in[1];
    const float* bi1    = (const float*)d_in[2];
    const float* wi2    = (const float*)d_in[3];
    const float* bi2    = (const float*)d_in[4];
    const float* w_in   = (const float*)d_in[5];
    const float* b_in   = (const float*)d_in[6];
    const float* w_hid  = (const float*)d_in[7];
    const float* b_hid  = (const float*)d_in[8];
    const float* w_out  = (const float*)d_in[9];
    const float* b_out  = (const float*)d_in[10];
    const float* w_proj = (const float*)d_in[11];
    const float* b_proj = (const float*)d_in[12];

    float* zT   = (float*)d_out;                       // B*T*H
    float* outp = zT + (size_t)BB * TT * HH;           // B*T*F
    float* mask = outp + (size_t)BB * TT * FF;         // B*T

    ncde_main<<<dim3(BB), dim3(512), 0, stream>>>(
        x, wi1, bi1, wi2, bi2, w_in, b_in, w_hid, b_hid, w_out, b_out, zT);
    ncde_proj<<<dim3((BB * TT) / 16), dim3(256), 0, stream>>>(
        zT, w_proj, b_proj, outp, mask);
}